// Round 5
// baseline (1288.343 us; speedup 1.0000x reference)
//
#include <hip/hip_runtime.h>
#include <stdint.h>

#define B_ 2
#define E_ 8
#define N_ 1024
#define D_ 1024
#define H_ 4096

typedef float f32x4 __attribute__((ext_vector_type(4)));
typedef __bf16 bf16x8 __attribute__((ext_vector_type(8)));
typedef __attribute__((address_space(3))) const unsigned short lds_cus;

__device__ __forceinline__ unsigned short f2bf(float f) {
  union { float f; uint32_t u; } v; v.f = f;
  uint32_t u = v.u;
  return (unsigned short)((u + 0x7FFFu + ((u >> 16) & 1u)) >> 16);  // RNE
}

__device__ __forceinline__ void gload_lds16(const unsigned short* g, unsigned short* l) {
  __builtin_amdgcn_global_load_lds(
      (__attribute__((address_space(1))) void*)g,
      (__attribute__((address_space(3))) void*)l,
      16, 0, 0);
}

__device__ __forceinline__ bf16x8 lds_read_b128(lds_cus* p) {
  bf16x8 r;
  asm volatile("ds_read_b128 %0, %1" : "=v"(r) : "v"(p));
  return r;
}

// ---- elementwise fp32 -> bf16 convert (x) ----
__global__ void cvt_x_kernel(const float* __restrict__ in, unsigned short* __restrict__ out, int n4) {
  int idx = blockIdx.x * blockDim.x + threadIdx.x;
  int stride = gridDim.x * blockDim.x;
  const float4* in4 = (const float4*)in;
  ushort4* out4 = (ushort4*)out;
  for (int i = idx; i < n4; i += stride) {
    float4 f = in4[i];
    ushort4 o;
    o.x = f2bf(f.x); o.y = f2bf(f.y); o.z = f2bf(f.z); o.w = f2bf(f.w);
    out4[i] = o;
  }
}

// ---- tiled transpose + convert: in fp32 [R][C] per expert -> out bf16 [C][R] ----
__global__ void transpose_cvt_kernel(const float* __restrict__ in, unsigned short* __restrict__ out,
                                     int R, int C) {
  __shared__ float tile[32][33];
  const size_t eoff = (size_t)blockIdx.z * R * C;
  const float* src = in + eoff;
  unsigned short* dst = out + eoff;
  const int c0 = blockIdx.x * 32, r0 = blockIdx.y * 32;
  const int tx = threadIdx.x, ty = threadIdx.y;
#pragma unroll
  for (int i = 0; i < 4; ++i)
    tile[ty + 8 * i][tx] = src[(size_t)(r0 + ty + 8 * i) * C + c0 + tx];
  __syncthreads();
#pragma unroll
  for (int i = 0; i < 4; ++i)
    dst[(size_t)(c0 + ty + 8 * i) * R + r0 + tx] = f2bf(tile[tx][ty + 8 * i]);
}

// ============================================================================
// REAL kernel (unchanged from R4): 256x256 tile, BK=64, 8-wave, 4-phase/K-tile.
// ============================================================================
template <int K, int NCOLS, bool GELU>
__global__ __launch_bounds__(512, 2)
void gemm256_kernel(const unsigned short* __restrict__ A,
                    const unsigned short* __restrict__ Bt,
                    const float* __restrict__ bias,
                    unsigned short* __restrict__ OutBf,
                    float* __restrict__ OutF) {
  constexpr int MT = 2048 / 256;
  constexpr int NTl = NCOLS / 256;
  constexpr int NT = K / 64;

  __shared__ __align__(16) unsigned short A0k0[8192], A0k1[8192], B0k0[8192], B0k1[8192];
  __shared__ __align__(16) unsigned short A1k0[8192], A1k1[8192], B1k0[8192], B1k1[8192];

  const int nwg = gridDim.x;
  const int flat = blockIdx.x;
  const int swz = (flat & 7) * (nwg >> 3) + (flat >> 3);
  const int e = swz / (MT * NTl);
  const int rem = swz - e * (MT * NTl);
  const int nt = rem / MT;
  const int mt = rem - nt * MT;

  const int m0 = mt * 256;
  const int n0 = nt * 256;
  const int b = m0 >> 10;
  const int nl = m0 & 1023;
  const size_t arow0 = (size_t)((b * E_ + e) * N_ + nl);

  const unsigned short* Ab = A + arow0 * K;
  const unsigned short* Bb = Bt + ((size_t)e * NCOLS + n0) * K;

  const int tid = threadIdx.x;
  const int w = tid >> 6;
  const int lane = tid & 63;
  const int wr = w >> 2;
  const int wc = w & 3;
  const int fr = lane & 15;
  const int kg = lane >> 4;
  const int sxor = kg ^ ((lane >> 1) & 3);

  const int scol = (((lane & 3) ^ ((lane >> 3) & 3)) << 3);
  const int srow0 = w * 32 + (lane >> 2);
  const int srow1 = w * 32 + 16 + (lane >> 2);
  const unsigned short* aS0 = Ab + (size_t)srow0 * K + scol;
  const unsigned short* aS1 = Ab + (size_t)srow1 * K + scol;
  const unsigned short* bS0 = Bb + (size_t)srow0 * K + scol;
  const unsigned short* bS1 = Bb + (size_t)srow1 * K + scol;

  const int aBase = (wr * 128 + fr) * 32 + sxor * 8;
  const int bBase = (wc * 64 + fr) * 32 + sxor * 8;

#define STAGE(ARR, S0_, S1_, t, kh) do {                           \
    const size_t ko_ = (size_t)(t) * 64 + (kh) * 32;               \
    gload_lds16(S0_ + ko_, &ARR[w * 1024]);                        \
    gload_lds16(S1_ + ko_, &ARR[w * 1024 + 512]);                  \
  } while (0)

  f32x4 acc[8][4];
#pragma unroll
  for (int i = 0; i < 8; ++i)
#pragma unroll
    for (int j = 0; j < 4; ++j)
      acc[i][j] = (f32x4){0.f, 0.f, 0.f, 0.f};

  STAGE(A0k0, aS0, aS1, 0, 0); STAGE(B0k0, bS0, bS1, 0, 0);
  STAGE(A0k1, aS0, aS1, 0, 1); STAGE(B0k1, bS0, bS1, 0, 1);
  STAGE(A1k0, aS0, aS1, 1, 0); STAGE(B1k0, bS0, bS1, 1, 0);
  asm volatile("s_waitcnt vmcnt(4)" ::: "memory");
  __builtin_amdgcn_s_barrier();

#define WAIT_LGKM() do {                                                      \
    asm volatile("s_waitcnt lgkmcnt(0)");                                     \
    __builtin_amdgcn_sched_barrier(0);                                        \
  } while (0)

#define MFMA_CLUSTER(ROFF)                                                    \
    __builtin_amdgcn_s_setprio(1);                                            \
    _Pragma("unroll")                                                         \
    for (int mi = 0; mi < 4; ++mi)                                            \
      _Pragma("unroll")                                                       \
      for (int ni = 0; ni < 4; ++ni)                                          \
        acc[(ROFF) + mi][ni] =                                                \
            __builtin_amdgcn_mfma_f32_16x16x32_bf16(av[mi], bv[ni],           \
                                                    acc[(ROFF) + mi][ni], 0, 0, 0); \
    __builtin_amdgcn_s_setprio(0);

#define ITER(t, CA0, CA1, CB0, CB1, NA1, NB1) do {                            \
    bf16x8 av[4], bv[4];                                                      \
    _Pragma("unroll")                                                         \
    for (int i = 0; i < 4; ++i) {                                             \
      av[i] = lds_read_b128((lds_cus*)&CA0[aBase + i * 512]);                 \
      bv[i] = lds_read_b128((lds_cus*)&CB0[bBase + i * 512]);                 \
    }                                                                         \
    if ((t) + 1 < NT) STAGE(NA1, aS0, aS1, (t) + 1, 1);                       \
    __builtin_amdgcn_s_barrier();                                             \
    WAIT_LGKM();                                                              \
    MFMA_CLUSTER(0)                                                           \
    __builtin_amdgcn_s_barrier();                                             \
    _Pragma("unroll")                                                         \
    for (int i = 0; i < 4; ++i)                                               \
      av[i] = lds_read_b128((lds_cus*)&CA0[aBase + 2048 + i * 512]);          \
    if ((t) + 1 < NT) STAGE(NB1, bS0, bS1, (t) + 1, 1);                       \
    __builtin_amdgcn_s_barrier();                                             \
    WAIT_LGKM();                                                              \
    MFMA_CLUSTER(4)                                                           \
    __builtin_amdgcn_s_barrier();                                             \
    _Pragma("unroll")                                                         \
    for (int i = 0; i < 4; ++i) {                                             \
      av[i] = lds_read_b128((lds_cus*)&CA1[aBase + i * 512]);                 \
      bv[i] = lds_read_b128((lds_cus*)&CB1[bBase + i * 512]);                 \
    }                                                                         \
    if ((t) + 2 < NT) STAGE(CA0, aS0, aS1, (t) + 2, 0);                       \
    __builtin_amdgcn_s_barrier();                                             \
    WAIT_LGKM();                                                              \
    MFMA_CLUSTER(0)                                                           \
    __builtin_amdgcn_s_barrier();                                             \
    _Pragma("unroll")                                                         \
    for (int i = 0; i < 4; ++i)                                               \
      av[i] = lds_read_b128((lds_cus*)&CA1[aBase + 2048 + i * 512]);          \
    if ((t) + 2 < NT) STAGE(CB0, bS0, bS1, (t) + 2, 0);                       \
    __builtin_amdgcn_s_barrier();                                             \
    WAIT_LGKM();                                                              \
    MFMA_CLUSTER(4)                                                           \
    if ((t) + 2 < NT) { asm volatile("s_waitcnt vmcnt(4)" ::: "memory"); }    \
    else              { asm volatile("s_waitcnt vmcnt(0)" ::: "memory"); }    \
    __builtin_amdgcn_s_barrier();                                             \
  } while (0)

#pragma unroll 1
  for (int tt = 0; tt < NT; tt += 2) {
    ITER(tt,     A0k0, A0k1, B0k0, B0k1, A1k1, B1k1);
    ITER(tt + 1, A1k0, A1k1, B1k0, B1k1, A0k1, B0k1);
  }

#undef ITER
#undef MFMA_CLUSTER
#undef WAIT_LGKM
#undef STAGE

  const int rb = kg * 4;
#pragma unroll
  for (int ni = 0; ni < 4; ++ni) {
    const int gc = n0 + wc * 64 + ni * 16 + fr;
    const float bval = bias[(size_t)e * NCOLS + gc];
#pragma unroll
    for (int MI = 0; MI < 8; ++MI) {
      const size_t orow = arow0 + (size_t)(wr * 128 + MI * 16 + rb);
#pragma unroll
      for (int j = 0; j < 4; ++j) {
        float v = acc[MI][ni][j] + bval;
        if constexpr (GELU) {
          float g = 0.5f * v * (1.0f + erff(v * 0.70710678118654752f));
          OutBf[(orow + j) * NCOLS + gc] = f2bf(g);
        } else {
          OutF[(orow + j) * NCOLS + gc] = v;
        }
      }
    }
  }
}

// ============================================================================
// ABLATION PROBE (timing-only; writes dead scratch): software-pipelined K-loop.
// In-tile ds_read read-ahead + counted lgkmcnt(4/8) + 3 barriers/K-tile
// (vs 8 drain-0 phases in the real kernel). GEMM2 shape, 3 passes so it tops
// the rocprof table. Races would corrupt scratch only.
// ============================================================================
__global__ __launch_bounds__(512, 2)
void abl_pipe(const unsigned short* __restrict__ A,    // hb  [16384][4096]
              const unsigned short* __restrict__ Bt,   // w2t [E][1024][4096]
              const float* __restrict__ bias,          // b2
              unsigned short* __restrict__ OutBf) {    // xb (scratch)
  constexpr int K = H_, NCOLS = D_;
  constexpr int MT = 8, NTl = NCOLS / 256, NT = K / 64;

  __shared__ __align__(16) unsigned short A0k0[8192], A0k1[8192], B0k0[8192], B0k1[8192];
  __shared__ __align__(16) unsigned short A1k0[8192], A1k1[8192], B1k0[8192], B1k1[8192];

  const int nwg = gridDim.x;
  const int flat = blockIdx.x;
  const int swz = (flat & 7) * (nwg >> 3) + (flat >> 3);
  const int e = swz / (MT * NTl);
  const int rem = swz - e * (MT * NTl);
  const int nt = rem / MT;
  const int mt = rem - nt * MT;

  const int m0 = mt * 256;
  const int n0 = nt * 256;
  const int b = m0 >> 10;
  const int nl = m0 & 1023;
  const size_t arow0 = (size_t)((b * E_ + e) * N_ + nl);

  const unsigned short* Ab = A + arow0 * K;
  const unsigned short* Bb = Bt + ((size_t)e * NCOLS + n0) * K;

  const int tid = threadIdx.x;
  const int w = tid >> 6;
  const int lane = tid & 63;
  const int wr = w >> 2;
  const int wc = w & 3;
  const int fr = lane & 15;
  const int kg = lane >> 4;
  const int sxor = kg ^ ((lane >> 1) & 3);

  const int scol = (((lane & 3) ^ ((lane >> 3) & 3)) << 3);
  const int srow0 = w * 32 + (lane >> 2);
  const int srow1 = w * 32 + 16 + (lane >> 2);
  const unsigned short* aS0 = Ab + (size_t)srow0 * K + scol;
  const unsigned short* aS1 = Ab + (size_t)srow1 * K + scol;
  const unsigned short* bS0 = Bb + (size_t)srow0 * K + scol;
  const unsigned short* bS1 = Bb + (size_t)srow1 * K + scol;

  const int aBase = (wr * 128 + fr) * 32 + sxor * 8;
  const int bBase = (wc * 64 + fr) * 32 + sxor * 8;

#define STAGE(ARR, S0_, S1_, t, kh) do {                           \
    const size_t ko_ = (size_t)(t) * 64 + (kh) * 32;               \
    gload_lds16(S0_ + ko_, &ARR[w * 1024]);                        \
    gload_lds16(S1_ + ko_, &ARR[w * 1024 + 512]);                  \
  } while (0)

  f32x4 acc[8][4];
#pragma unroll
  for (int i = 0; i < 8; ++i)
#pragma unroll
    for (int j = 0; j < 4; ++j)
      acc[i][j] = (f32x4){0.f, 0.f, 0.f, 0.f};

#define MFMA_C(ROFF, AV, BV)                                                  \
    __builtin_amdgcn_s_setprio(1);                                            \
    _Pragma("unroll")                                                         \
    for (int mi = 0; mi < 4; ++mi)                                            \
      _Pragma("unroll")                                                       \
      for (int ni = 0; ni < 4; ++ni)                                          \
        acc[(ROFF) + mi][ni] =                                                \
            __builtin_amdgcn_mfma_f32_16x16x32_bf16(AV[mi], BV[ni],           \
                                                    acc[(ROFF) + mi][ni], 0, 0, 0); \
    __builtin_amdgcn_s_setprio(0);

  // Per K-tile: 4 MFMA windows, counted lgkm waits, 3 barriers.
  // w1: read W1a(avA<-CA0.lo, bvA<-CB0) + W1b(avB<-CA0.hi); stage NA1;
  //     lgkm(4) -> C0(avA,bvA)
  // w2: read W2(avA<-CA1.lo, bvB<-CB1); stage NB1; lgkm(8)[W1b done]; BARRIER
  //     -> C1(avB,bvA)
  // w3: read W3(avB<-CA1.hi); stage CA0(t+2) [licensed: barrier after W1 done];
  //     lgkm(4)[W2 done]; BARRIER -> C2(avA,bvB)
  // w4: stage CB0(t+2); lgkm(0)[W3 done] -> C3(avB,bvB); boundary vmcnt; BARRIER
#define ITER5(t, CA0, CA1, CB0, CB1, NA1, NB1) do {                           \
    bf16x8 avA[4], avB[4], bvA[4], bvB[4];                                    \
    _Pragma("unroll")                                                         \
    for (int i = 0; i < 4; ++i) {                                             \
      avA[i] = lds_read_b128((lds_cus*)&CA0[aBase + i * 512]);                \
      bvA[i] = lds_read_b128((lds_cus*)&CB0[bBase + i * 512]);                \
    }                                                                         \
    _Pragma("unroll")                                                         \
    for (int i = 0; i < 4; ++i)                                               \
      avB[i] = lds_read_b128((lds_cus*)&CA0[aBase + 2048 + i * 512]);         \
    if ((t) + 1 < NT) STAGE(NA1, aS0, aS1, (t) + 1, 1);                       \
    asm volatile("s_waitcnt lgkmcnt(4)");                                     \
    __builtin_amdgcn_sched_barrier(0);                                        \
    MFMA_C(0, avA, bvA)                                                       \
    _Pragma("unroll")                                                         \
    for (int i = 0; i < 4; ++i) {                                             \
      avA[i] = lds_read_b128((lds_cus*)&CA1[aBase + i * 512]);                \
      bvB[i] = lds_read_b128((lds_cus*)&CB1[bBase + i * 512]);                \
    }                                                                         \
    if ((t) + 1 < NT) STAGE(NB1, bS0, bS1, (t) + 1, 1);                       \
    asm volatile("s_waitcnt lgkmcnt(8)");                                     \
    __builtin_amdgcn_sched_barrier(0);                                        \
    __builtin_amdgcn_s_barrier();                                             \
    __builtin_amdgcn_sched_barrier(0);                                        \
    MFMA_C(4, avB, bvA)                                                       \
    _Pragma("unroll")                                                         \
    for (int i = 0; i < 4; ++i)                                               \
      avB[i] = lds_read_b128((lds_cus*)&CA1[aBase + 2048 + i * 512]);         \
    if ((t) + 2 < NT) STAGE(CA0, aS0, aS1, (t) + 2, 0);                       \
    asm volatile("s_waitcnt lgkmcnt(4)");                                     \
    __builtin_amdgcn_sched_barrier(0);                                        \
    __builtin_amdgcn_s_barrier();                                             \
    __builtin_amdgcn_sched_barrier(0);                                        \
    MFMA_C(0, avA, bvB)                                                       \
    if ((t) + 2 < NT) STAGE(CB0, bS0, bS1, (t) + 2, 0);                       \
    asm volatile("s_waitcnt lgkmcnt(0)");                                     \
    __builtin_amdgcn_sched_barrier(0);                                        \
    MFMA_C(4, avB, bvB)                                                       \
    if ((t) + 2 < NT) { asm volatile("s_waitcnt vmcnt(4)" ::: "memory"); }    \
    else              { asm volatile("s_waitcnt vmcnt(0)" ::: "memory"); }    \
    __builtin_amdgcn_s_barrier();                                             \
  } while (0)

#pragma unroll 1
  for (int pass = 0; pass < 3; ++pass) {
    STAGE(A0k0, aS0, aS1, 0, 0); STAGE(B0k0, bS0, bS1, 0, 0);
    STAGE(A0k1, aS0, aS1, 0, 1); STAGE(B0k1, bS0, bS1, 0, 1);
    STAGE(A1k0, aS0, aS1, 1, 0); STAGE(B1k0, bS0, bS1, 1, 0);
    asm volatile("s_waitcnt vmcnt(4)" ::: "memory");
    __builtin_amdgcn_s_barrier();
#pragma unroll 1
    for (int tt = 0; tt < NT; tt += 2) {
      ITER5(tt,     A0k0, A0k1, B0k0, B0k1, A1k1, B1k1);
      ITER5(tt + 1, A1k0, A1k1, B1k0, B1k1, A0k1, B0k1);
    }
  }

#undef ITER5
#undef MFMA_C
#undef STAGE

  const int rb = kg * 4;
#pragma unroll
  for (int ni = 0; ni < 4; ++ni) {
    const int gc = n0 + wc * 64 + ni * 16 + fr;
    const float bval = bias[(size_t)e * NCOLS + gc];
#pragma unroll
    for (int MI = 0; MI < 8; ++MI) {
      const size_t orow = arow0 + (size_t)(wr * 128 + MI * 16 + rb);
#pragma unroll
      for (int j = 0; j < 4; ++j) {
        float v = acc[MI][ni][j] + bval;
        float g = 0.5f * v * (1.0f + erff(v * 0.70710678118654752f));
        OutBf[(orow + j) * NCOLS + gc] = f2bf(g);
      }
    }
  }
}

extern "C" void kernel_launch(void* const* d_in, const int* in_sizes, int n_in,
                              void* d_out, int out_size, void* d_ws, size_t ws_size,
                              hipStream_t stream) {
  const float* x  = (const float*)d_in[0];
  const float* w1 = (const float*)d_in[1];
  const float* b1 = (const float*)d_in[2];
  const float* w2 = (const float*)d_in[3];
  const float* b2 = (const float*)d_in[4];
  float* out = (float*)d_out;

  const size_t xN  = (size_t)B_ * E_ * N_ * D_;
  const size_t w1N = (size_t)E_ * D_ * H_;
  const size_t w2N = (size_t)E_ * H_ * D_;
  const size_t hN  = (size_t)B_ * E_ * N_ * H_;
  const size_t needed = (xN + w1N + w2N + hN) * 2;
  if (ws_size < needed) return;

  unsigned short* xb  = (unsigned short*)d_ws;
  unsigned short* w1t = xb + xN;
  unsigned short* w2t = w1t + w1N;
  unsigned short* hb  = w2t + w2N;

  cvt_x_kernel<<<2048, 256, 0, stream>>>(x, xb, (int)(xN / 4));
  dim3 tb(32, 8);
  transpose_cvt_kernel<<<dim3(H_ / 32, D_ / 32, E_), tb, 0, stream>>>(w1, w1t, D_, H_);
  transpose_cvt_kernel<<<dim3(D_ / 32, H_ / 32, E_), tb, 0, stream>>>(w2, w2t, H_, D_);

  gemm256_kernel<D_, H_, true><<<8 * (H_ / 256) * E_, 512, 0, stream>>>(xb, w1t, b1, hb, nullptr);
  gemm256_kernel<H_, D_, false><<<8 * (D_ / 256) * E_, 512, 0, stream>>>(hb, w2t, b2, nullptr, out);

  // Diagnostic probe (after real GEMMs; xb is dead, output unaffected).
  abl_pipe<<<8 * (D_ / 256) * E_, 512, 0, stream>>>(hb, w2t, b2, xb);
}

// Round 6
// 514.542 us; speedup vs baseline: 2.5039x; 2.5039x over previous
//
#include <hip/hip_runtime.h>
#include <stdint.h>

#define B_ 2
#define E_ 8
#define N_ 1024
#define D_ 1024
#define H_ 4096

typedef float f32x4 __attribute__((ext_vector_type(4)));
typedef __bf16 bf16x8 __attribute__((ext_vector_type(8)));
typedef __attribute__((address_space(3))) const unsigned short lds_cus;

__device__ __forceinline__ unsigned short f2bf(float f) {
  union { float f; uint32_t u; } v; v.f = f;
  uint32_t u = v.u;
  return (unsigned short)((u + 0x7FFFu + ((u >> 16) & 1u)) >> 16);  // RNE
}

// tanh-form GELU: 0.5x(1+tanh(0.79788456(x+0.044715x^3))).
// Max |delta| vs exact erf-GELU ~1e-3 -- well inside threshold headroom.
// ~10 VALU ops vs ocml erff's ~35+ with branches.
__device__ __forceinline__ float gelu_fast(float x) {
  float x3 = x * x * x;
  float y = 0.79788456080286536f * (x + 0.044715f * x3);
  float e = __expf(2.0f * y);
  float t = 1.0f - 2.0f / (e + 1.0f);   // tanh(y)
  return 0.5f * x * (1.0f + t);
}

__device__ __forceinline__ void gload_lds16(const unsigned short* g, unsigned short* l) {
  __builtin_amdgcn_global_load_lds(
      (__attribute__((address_space(1))) void*)g,
      (__attribute__((address_space(3))) void*)l,
      16, 0, 0);
}

__device__ __forceinline__ bf16x8 lds_read_b128(lds_cus* p) {
  bf16x8 r;
  asm volatile("ds_read_b128 %0, %1" : "=v"(r) : "v"(p));
  return r;
}

// ---- elementwise fp32 -> bf16 convert (x) ----
__global__ void cvt_x_kernel(const float* __restrict__ in, unsigned short* __restrict__ out, int n4) {
  int idx = blockIdx.x * blockDim.x + threadIdx.x;
  int stride = gridDim.x * blockDim.x;
  const float4* in4 = (const float4*)in;
  ushort4* out4 = (ushort4*)out;
  for (int i = idx; i < n4; i += stride) {
    float4 f = in4[i];
    ushort4 o;
    o.x = f2bf(f.x); o.y = f2bf(f.y); o.z = f2bf(f.z); o.w = f2bf(f.w);
    out4[i] = o;
  }
}

// ---- tiled transpose + convert: in fp32 [R][C] per expert -> out bf16 [C][R] ----
__global__ void transpose_cvt_kernel(const float* __restrict__ in, unsigned short* __restrict__ out,
                                     int R, int C) {
  __shared__ float tile[32][33];
  const size_t eoff = (size_t)blockIdx.z * R * C;
  const float* src = in + eoff;
  unsigned short* dst = out + eoff;
  const int c0 = blockIdx.x * 32, r0 = blockIdx.y * 32;
  const int tx = threadIdx.x, ty = threadIdx.y;
#pragma unroll
  for (int i = 0; i < 4; ++i)
    tile[ty + 8 * i][tx] = src[(size_t)(r0 + ty + 8 * i) * C + c0 + tx];
  __syncthreads();
#pragma unroll
  for (int i = 0; i < 4; ++i)
    dst[(size_t)(c0 + ty + 8 * i) * R + r0 + tx] = f2bf(tile[tx][ty + 8 * i]);
}

// ============================================================================
// 256x256-tile, BK=64, 8-wave, 4-phase/K-tile bf16 MFMA GEMM (R4 schedule).
// NEW (R6): NTG n-tiles per block -- each block loops over NTG consecutive
// n-tiles of the same (e, mt), equalizing both GEMMs at 256 blocks / 1 round
// (1 block/CU), so prologue/epilogue tails overlap instead of serializing
// across 4 dispatch rounds. GELU epilogue uses tanh-form (no erff).
// ============================================================================
template <int K, int NCOLS, int NTG, bool GELU>
__global__ __launch_bounds__(512, 2)
void gemm256_kernel(const unsigned short* __restrict__ A,
                    const unsigned short* __restrict__ Bt,
                    const float* __restrict__ bias,
                    unsigned short* __restrict__ OutBf,
                    float* __restrict__ OutF) {
  constexpr int MT = 2048 / 256;     // M tiles per expert
  constexpr int NTl = NCOLS / 256;   // N tiles total
  constexpr int G = NTl / NTG;       // N groups per expert
  constexpr int NT = K / 64;         // K tiles (even)

  __shared__ __align__(16) unsigned short A0k0[8192], A0k1[8192], B0k0[8192], B0k1[8192];
  __shared__ __align__(16) unsigned short A1k0[8192], A1k1[8192], B1k0[8192], B1k1[8192];

  // T1: bijective XCD swizzle (grid = 256 for both GEMMs)
  const int nwg = gridDim.x;
  const int flat = blockIdx.x;
  const int swz = (flat & 7) * (nwg >> 3) + (flat >> 3);
  const int e = swz / (MT * G);
  const int rem = swz - e * (MT * G);
  const int ng = rem / MT;
  const int mt = rem - ng * MT;

  const int m0 = mt * 256;
  const int b = m0 >> 10;
  const int nl = m0 & 1023;
  const size_t arow0 = (size_t)((b * E_ + e) * N_ + nl);

  const unsigned short* Ab = A + arow0 * K;

  const int tid = threadIdx.x;
  const int w = tid >> 6;
  const int lane = tid & 63;
  const int wr = w >> 2;
  const int wc = w & 3;
  const int fr = lane & 15;
  const int kg = lane >> 4;
  const int sxor = kg ^ ((lane >> 1) & 3);

  const int scol = (((lane & 3) ^ ((lane >> 3) & 3)) << 3);
  const int srow0 = w * 32 + (lane >> 2);
  const int srow1 = w * 32 + 16 + (lane >> 2);
  const unsigned short* aS0 = Ab + (size_t)srow0 * K + scol;
  const unsigned short* aS1 = Ab + (size_t)srow1 * K + scol;

  const int aBase = (wr * 128 + fr) * 32 + sxor * 8;
  const int bBase = (wc * 64 + fr) * 32 + sxor * 8;
  const int rb = kg * 4;

#define STAGE(ARR, S0_, S1_, t, kh) do {                           \
    const size_t ko_ = (size_t)(t) * 64 + (kh) * 32;               \
    gload_lds16(S0_ + ko_, &ARR[w * 1024]);                        \
    gload_lds16(S1_ + ko_, &ARR[w * 1024 + 512]);                  \
  } while (0)

#define WAIT_LGKM() do {                                                      \
    asm volatile("s_waitcnt lgkmcnt(0)");                                     \
    __builtin_amdgcn_sched_barrier(0);                                        \
  } while (0)

#define MFMA_CLUSTER(ROFF)                                                    \
    __builtin_amdgcn_s_setprio(1);                                            \
    _Pragma("unroll")                                                         \
    for (int mi = 0; mi < 4; ++mi)                                            \
      _Pragma("unroll")                                                       \
      for (int ni = 0; ni < 4; ++ni)                                          \
        acc[(ROFF) + mi][ni] =                                                \
            __builtin_amdgcn_mfma_f32_16x16x32_bf16(av[mi], bv[ni],           \
                                                    acc[(ROFF) + mi][ni], 0, 0, 0); \
    __builtin_amdgcn_s_setprio(0);

#define ITER(t, CA0, CA1, CB0, CB1, NA1, NB1) do {                            \
    bf16x8 av[4], bv[4];                                                      \
    _Pragma("unroll")                                                         \
    for (int i = 0; i < 4; ++i) {                                             \
      av[i] = lds_read_b128((lds_cus*)&CA0[aBase + i * 512]);                 \
      bv[i] = lds_read_b128((lds_cus*)&CB0[bBase + i * 512]);                 \
    }                                                                         \
    if ((t) + 1 < NT) STAGE(NA1, aS0, aS1, (t) + 1, 1);                       \
    __builtin_amdgcn_s_barrier();                                             \
    WAIT_LGKM();                                                              \
    MFMA_CLUSTER(0)                                                           \
    __builtin_amdgcn_s_barrier();                                             \
    _Pragma("unroll")                                                         \
    for (int i = 0; i < 4; ++i)                                               \
      av[i] = lds_read_b128((lds_cus*)&CA0[aBase + 2048 + i * 512]);          \
    if ((t) + 1 < NT) STAGE(NB1, bS0, bS1, (t) + 1, 1);                       \
    __builtin_amdgcn_s_barrier();                                             \
    WAIT_LGKM();                                                              \
    MFMA_CLUSTER(4)                                                           \
    __builtin_amdgcn_s_barrier();                                             \
    _Pragma("unroll")                                                         \
    for (int i = 0; i < 4; ++i) {                                             \
      av[i] = lds_read_b128((lds_cus*)&CA1[aBase + i * 512]);                 \
      bv[i] = lds_read_b128((lds_cus*)&CB1[bBase + i * 512]);                 \
    }                                                                         \
    if ((t) + 2 < NT) STAGE(CA0, aS0, aS1, (t) + 2, 0);                       \
    __builtin_amdgcn_s_barrier();                                             \
    WAIT_LGKM();                                                              \
    MFMA_CLUSTER(0)                                                           \
    __builtin_amdgcn_s_barrier();                                             \
    _Pragma("unroll")                                                         \
    for (int i = 0; i < 4; ++i)                                               \
      av[i] = lds_read_b128((lds_cus*)&CA1[aBase + 2048 + i * 512]);          \
    if ((t) + 2 < NT) STAGE(CB0, bS0, bS1, (t) + 2, 0);                       \
    __builtin_amdgcn_s_barrier();                                             \
    WAIT_LGKM();                                                              \
    MFMA_CLUSTER(4)                                                           \
    if ((t) + 2 < NT) { asm volatile("s_waitcnt vmcnt(4)" ::: "memory"); }    \
    else              { asm volatile("s_waitcnt vmcnt(0)" ::: "memory"); }    \
    __builtin_amdgcn_s_barrier();                                             \
  } while (0)

#pragma unroll 1
  for (int ig = 0; ig < NTG; ++ig) {
    const int nt = ng * NTG + ig;
    const int n0 = nt * 256;
    const unsigned short* Bb = Bt + ((size_t)e * NCOLS + n0) * K;
    const unsigned short* bS0 = Bb + (size_t)srow0 * K + scol;
    const unsigned short* bS1 = Bb + (size_t)srow1 * K + scol;

    f32x4 acc[8][4];
#pragma unroll
    for (int i = 0; i < 8; ++i)
#pragma unroll
      for (int j = 0; j < 4; ++j)
        acc[i][j] = (f32x4){0.f, 0.f, 0.f, 0.f};

    // prologue: tile0 fully + tile1 khalf0; 2 half-tiles (4 instrs) in flight
    STAGE(A0k0, aS0, aS1, 0, 0); STAGE(B0k0, bS0, bS1, 0, 0);
    STAGE(A0k1, aS0, aS1, 0, 1); STAGE(B0k1, bS0, bS1, 0, 1);
    STAGE(A1k0, aS0, aS1, 1, 0); STAGE(B1k0, bS0, bS1, 1, 0);
    asm volatile("s_waitcnt vmcnt(4)" ::: "memory");
    __builtin_amdgcn_s_barrier();

#pragma unroll 1
    for (int tt = 0; tt < NT; tt += 2) {
      ITER(tt,     A0k0, A0k1, B0k0, B0k1, A1k1, B1k1);
      ITER(tt + 1, A1k0, A1k1, B1k0, B1k1, A0k1, B0k1);
    }

    // epilogue: C/D layout col=lane&15, row=(lane>>4)*4+j
#pragma unroll
    for (int ni = 0; ni < 4; ++ni) {
      const int gc = n0 + wc * 64 + ni * 16 + fr;
      const float bval = bias[(size_t)e * NCOLS + gc];
#pragma unroll
      for (int MI = 0; MI < 8; ++MI) {
        const size_t orow = arow0 + (size_t)(wr * 128 + MI * 16 + rb);
#pragma unroll
        for (int j = 0; j < 4; ++j) {
          float v = acc[MI][ni][j] + bval;
          if constexpr (GELU) {
            OutBf[(orow + j) * NCOLS + gc] = f2bf(gelu_fast(v));
          } else {
            OutF[(orow + j) * NCOLS + gc] = v;
          }
        }
      }
    }
  }

#undef ITER
#undef MFMA_CLUSTER
#undef WAIT_LGKM
#undef STAGE
}

extern "C" void kernel_launch(void* const* d_in, const int* in_sizes, int n_in,
                              void* d_out, int out_size, void* d_ws, size_t ws_size,
                              hipStream_t stream) {
  const float* x  = (const float*)d_in[0];
  const float* w1 = (const float*)d_in[1];
  const float* b1 = (const float*)d_in[2];
  const float* w2 = (const float*)d_in[3];
  const float* b2 = (const float*)d_in[4];
  float* out = (float*)d_out;

  const size_t xN  = (size_t)B_ * E_ * N_ * D_;
  const size_t w1N = (size_t)E_ * D_ * H_;
  const size_t w2N = (size_t)E_ * H_ * D_;
  const size_t hN  = (size_t)B_ * E_ * N_ * H_;
  const size_t needed = (xN + w1N + w2N + hN) * 2;
  if (ws_size < needed) return;

  unsigned short* xb  = (unsigned short*)d_ws;
  unsigned short* w1t = xb + xN;   // [E][H][D] bf16
  unsigned short* w2t = w1t + w1N; // [E][D][H] bf16
  unsigned short* hb  = w2t + w2N; // [B][E][N][H] bf16

  cvt_x_kernel<<<2048, 256, 0, stream>>>(x, xb, (int)(xN / 4));
  dim3 tb(32, 8);
  transpose_cvt_kernel<<<dim3(H_ / 32, D_ / 32, E_), tb, 0, stream>>>(w1, w1t, D_, H_);
  transpose_cvt_kernel<<<dim3(D_ / 32, H_ / 32, E_), tb, 0, stream>>>(w2, w2t, H_, D_);

  // GEMM1: h = gelu(x @ w1 + b1); 256 blocks, each covers 4 n-tiles
  gemm256_kernel<D_, H_, 4, true><<<E_ * 8 * (H_ / 256 / 4), 512, 0, stream>>>(
      xb, w1t, b1, hb, nullptr);
  // GEMM2: out = h @ w2 + b2; 256 blocks, 1 n-tile each
  gemm256_kernel<H_, D_, 1, false><<<E_ * 8 * (D_ / 256), 512, 0, stream>>>(
      hb, w2t, b2, nullptr, out);
}

// Round 7
// 440.936 us; speedup vs baseline: 2.9218x; 1.1669x over previous
//
#include <hip/hip_runtime.h>
#include <stdint.h>

#define B_ 2
#define E_ 8
#define N_ 1024
#define D_ 1024
#define H_ 4096

typedef float f32x4 __attribute__((ext_vector_type(4)));
typedef __bf16 bf16x8 __attribute__((ext_vector_type(8)));
typedef __attribute__((address_space(3))) const unsigned short lds_cus;

__device__ __forceinline__ unsigned short f2bf(float f) {
  union { float f; uint32_t u; } v; v.f = f;
  uint32_t u = v.u;
  return (unsigned short)((u + 0x7FFFu + ((u >> 16) & 1u)) >> 16);  // RNE
}

// tanh-form GELU (max |delta| vs exact erf-GELU ~1e-3, inside threshold headroom)
__device__ __forceinline__ float gelu_fast(float x) {
  float x3 = x * x * x;
  float y = 0.79788456080286536f * (x + 0.044715f * x3);
  float e = __expf(2.0f * y);
  float t = 1.0f - 2.0f / (e + 1.0f);   // tanh(y)
  return 0.5f * x * (1.0f + t);
}

__device__ __forceinline__ void gload_lds16(const unsigned short* g, unsigned short* l) {
  __builtin_amdgcn_global_load_lds(
      (__attribute__((address_space(1))) void*)g,
      (__attribute__((address_space(3))) void*)l,
      16, 0, 0);
}

__device__ __forceinline__ bf16x8 lds_read_b128(lds_cus* p) {
  bf16x8 r;
  asm volatile("ds_read_b128 %0, %1" : "=v"(r) : "v"(p));
  return r;
}

// ---- elementwise fp32 -> bf16 convert (x) ----
__global__ void cvt_x_kernel(const float* __restrict__ in, unsigned short* __restrict__ out, int n4) {
  int idx = blockIdx.x * blockDim.x + threadIdx.x;
  int stride = gridDim.x * blockDim.x;
  const float4* in4 = (const float4*)in;
  ushort4* out4 = (ushort4*)out;
  for (int i = idx; i < n4; i += stride) {
    float4 f = in4[i];
    ushort4 o;
    o.x = f2bf(f.x); o.y = f2bf(f.y); o.z = f2bf(f.z); o.w = f2bf(f.w);
    out4[i] = o;
  }
}

// ---- tiled transpose + convert: in fp32 [R][C] per expert -> out bf16 [C][R] ----
__global__ void transpose_cvt_kernel(const float* __restrict__ in, unsigned short* __restrict__ out,
                                     int R, int C) {
  __shared__ float tile[32][33];
  const size_t eoff = (size_t)blockIdx.z * R * C;
  const float* src = in + eoff;
  unsigned short* dst = out + eoff;
  const int c0 = blockIdx.x * 32, r0 = blockIdx.y * 32;
  const int tx = threadIdx.x, ty = threadIdx.y;
#pragma unroll
  for (int i = 0; i < 4; ++i)
    tile[ty + 8 * i][tx] = src[(size_t)(r0 + ty + 8 * i) * C + c0 + tx];
  __syncthreads();
#pragma unroll
  for (int i = 0; i < 4; ++i)
    dst[(size_t)(c0 + ty + 8 * i) * R + r0 + tx] = f2bf(tile[tx][ty + 8 * i]);
}

// ============================================================================
// Common body: 256x256-tile, BK=64, 8-wave, 4-phase/K-tile bf16 MFMA GEMM
// (R4 schedule, R6 NTG grouping). R7: GELU epilogue stores with ni INNERMOST
// so each output row's 4x 32B bf16 chunks (128B contiguous) are written
// back-to-back -> full 64B sectors at L2 eviction -> no HBM partial-sector
// RMW (R6 measured WRITE_SIZE = 2.07x ideal with ni outermost).
// ============================================================================
template <int K, int NCOLS, int NTG, bool GELU>
__device__ __forceinline__ void gemm_body(const unsigned short* __restrict__ A,
                                          const unsigned short* __restrict__ Bt,
                                          const float* __restrict__ bias,
                                          unsigned short* __restrict__ OutBf,
                                          float* __restrict__ OutF) {
  constexpr int MT = 2048 / 256;
  constexpr int NTl = NCOLS / 256;
  constexpr int G = NTl / NTG;
  constexpr int NT = K / 64;

  __shared__ __align__(16) unsigned short A0k0[8192], A0k1[8192], B0k0[8192], B0k1[8192];
  __shared__ __align__(16) unsigned short A1k0[8192], A1k1[8192], B1k0[8192], B1k1[8192];

  const int nwg = gridDim.x;
  const int flat = blockIdx.x;
  const int swz = (flat & 7) * (nwg >> 3) + (flat >> 3);
  const int e = swz / (MT * G);
  const int rem = swz - e * (MT * G);
  const int ng = rem / MT;
  const int mt = rem - ng * MT;

  const int m0 = mt * 256;
  const int b = m0 >> 10;
  const int nl = m0 & 1023;
  const size_t arow0 = (size_t)((b * E_ + e) * N_ + nl);

  const unsigned short* Ab = A + arow0 * K;

  const int tid = threadIdx.x;
  const int w = tid >> 6;
  const int lane = tid & 63;
  const int wr = w >> 2;
  const int wc = w & 3;
  const int fr = lane & 15;
  const int kg = lane >> 4;
  const int sxor = kg ^ ((lane >> 1) & 3);

  const int scol = (((lane & 3) ^ ((lane >> 3) & 3)) << 3);
  const int srow0 = w * 32 + (lane >> 2);
  const int srow1 = w * 32 + 16 + (lane >> 2);
  const unsigned short* aS0 = Ab + (size_t)srow0 * K + scol;
  const unsigned short* aS1 = Ab + (size_t)srow1 * K + scol;

  const int aBase = (wr * 128 + fr) * 32 + sxor * 8;
  const int bBase = (wc * 64 + fr) * 32 + sxor * 8;
  const int rb = kg * 4;

#define STAGE(ARR, S0_, S1_, t, kh) do {                           \
    const size_t ko_ = (size_t)(t) * 64 + (kh) * 32;               \
    gload_lds16(S0_ + ko_, &ARR[w * 1024]);                        \
    gload_lds16(S1_ + ko_, &ARR[w * 1024 + 512]);                  \
  } while (0)

#define WAIT_LGKM() do {                                                      \
    asm volatile("s_waitcnt lgkmcnt(0)");                                     \
    __builtin_amdgcn_sched_barrier(0);                                        \
  } while (0)

#define MFMA_CLUSTER(ROFF)                                                    \
    __builtin_amdgcn_s_setprio(1);                                            \
    _Pragma("unroll")                                                         \
    for (int mi = 0; mi < 4; ++mi)                                            \
      _Pragma("unroll")                                                       \
      for (int ni = 0; ni < 4; ++ni)                                          \
        acc[(ROFF) + mi][ni] =                                                \
            __builtin_amdgcn_mfma_f32_16x16x32_bf16(av[mi], bv[ni],           \
                                                    acc[(ROFF) + mi][ni], 0, 0, 0); \
    __builtin_amdgcn_s_setprio(0);

#define ITER(t, CA0, CA1, CB0, CB1, NA1, NB1) do {                            \
    bf16x8 av[4], bv[4];                                                      \
    _Pragma("unroll")                                                         \
    for (int i = 0; i < 4; ++i) {                                             \
      av[i] = lds_read_b128((lds_cus*)&CA0[aBase + i * 512]);                 \
      bv[i] = lds_read_b128((lds_cus*)&CB0[bBase + i * 512]);                 \
    }                                                                         \
    if ((t) + 1 < NT) STAGE(NA1, aS0, aS1, (t) + 1, 1);                       \
    __builtin_amdgcn_s_barrier();                                             \
    WAIT_LGKM();                                                              \
    MFMA_CLUSTER(0)                                                           \
    __builtin_amdgcn_s_barrier();                                             \
    _Pragma("unroll")                                                         \
    for (int i = 0; i < 4; ++i)                                               \
      av[i] = lds_read_b128((lds_cus*)&CA0[aBase + 2048 + i * 512]);          \
    if ((t) + 1 < NT) STAGE(NB1, bS0, bS1, (t) + 1, 1);                       \
    __builtin_amdgcn_s_barrier();                                             \
    WAIT_LGKM();                                                              \
    MFMA_CLUSTER(4)                                                           \
    __builtin_amdgcn_s_barrier();                                             \
    _Pragma("unroll")                                                         \
    for (int i = 0; i < 4; ++i) {                                             \
      av[i] = lds_read_b128((lds_cus*)&CA1[aBase + i * 512]);                 \
      bv[i] = lds_read_b128((lds_cus*)&CB1[bBase + i * 512]);                 \
    }                                                                         \
    if ((t) + 2 < NT) STAGE(CA0, aS0, aS1, (t) + 2, 0);                       \
    __builtin_amdgcn_s_barrier();                                             \
    WAIT_LGKM();                                                              \
    MFMA_CLUSTER(0)                                                           \
    __builtin_amdgcn_s_barrier();                                             \
    _Pragma("unroll")                                                         \
    for (int i = 0; i < 4; ++i)                                               \
      av[i] = lds_read_b128((lds_cus*)&CA1[aBase + 2048 + i * 512]);          \
    if ((t) + 2 < NT) STAGE(CB0, bS0, bS1, (t) + 2, 0);                       \
    __builtin_amdgcn_s_barrier();                                             \
    WAIT_LGKM();                                                              \
    MFMA_CLUSTER(4)                                                           \
    if ((t) + 2 < NT) { asm volatile("s_waitcnt vmcnt(4)" ::: "memory"); }    \
    else              { asm volatile("s_waitcnt vmcnt(0)" ::: "memory"); }    \
    __builtin_amdgcn_s_barrier();                                             \
  } while (0)

#pragma unroll 1
  for (int ig = 0; ig < NTG; ++ig) {
    const int nt = ng * NTG + ig;
    const int n0 = nt * 256;
    const unsigned short* Bb = Bt + ((size_t)e * NCOLS + n0) * K;
    const unsigned short* bS0 = Bb + (size_t)srow0 * K + scol;
    const unsigned short* bS1 = Bb + (size_t)srow1 * K + scol;

    f32x4 acc[8][4];
#pragma unroll
    for (int i = 0; i < 8; ++i)
#pragma unroll
      for (int j = 0; j < 4; ++j)
        acc[i][j] = (f32x4){0.f, 0.f, 0.f, 0.f};

    STAGE(A0k0, aS0, aS1, 0, 0); STAGE(B0k0, bS0, bS1, 0, 0);
    STAGE(A0k1, aS0, aS1, 0, 1); STAGE(B0k1, bS0, bS1, 0, 1);
    STAGE(A1k0, aS0, aS1, 1, 0); STAGE(B1k0, bS0, bS1, 1, 0);
    asm volatile("s_waitcnt vmcnt(4)" ::: "memory");
    __builtin_amdgcn_s_barrier();

#pragma unroll 1
    for (int tt = 0; tt < NT; tt += 2) {
      ITER(tt,     A0k0, A0k1, B0k0, B0k1, A1k1, B1k1);
      ITER(tt + 1, A1k0, A1k1, B1k0, B1k1, A0k1, B0k1);
    }

    // epilogue: C/D layout col=lane&15, row=(lane>>4)*4+j
    if constexpr (GELU) {
      // ni INNERMOST: per row, 4 back-to-back 2B-store instrs cover cols
      // [wc*64 .. wc*64+63] = 128B contiguous -> full 64B sectors.
      float bval[4];
#pragma unroll
      for (int ni = 0; ni < 4; ++ni)
        bval[ni] = bias[(size_t)e * NCOLS + n0 + wc * 64 + ni * 16 + fr];
      const size_t gcb = (size_t)n0 + wc * 64 + fr;
#pragma unroll
      for (int MI = 0; MI < 8; ++MI) {
#pragma unroll
        for (int j = 0; j < 4; ++j) {
          const size_t orow = arow0 + (size_t)(wr * 128 + MI * 16 + rb + j);
          unsigned short* rp = OutBf + orow * NCOLS + gcb;
#pragma unroll
          for (int ni = 0; ni < 4; ++ni) {
            float v = acc[MI][ni][j] + bval[ni];
            rp[ni * 16] = f2bf(gelu_fast(v));
          }
        }
      }
    } else {
#pragma unroll
      for (int ni = 0; ni < 4; ++ni) {
        const int gc = n0 + wc * 64 + ni * 16 + fr;
        const float bval = bias[(size_t)e * NCOLS + gc];
#pragma unroll
        for (int MI = 0; MI < 8; ++MI) {
          const size_t orow = arow0 + (size_t)(wr * 128 + MI * 16 + rb);
#pragma unroll
          for (int j = 0; j < 4; ++j)
            OutF[(orow + j) * NCOLS + gc] = acc[MI][ni][j] + bval;
        }
      }
    }
  }

#undef ITER
#undef MFMA_CLUSTER
#undef WAIT_LGKM
#undef STAGE
}

// Distinct names so rocprof attributes each GEMM separately.
__global__ __launch_bounds__(512, 2)
void gemm_mlp1(const unsigned short* __restrict__ A, const unsigned short* __restrict__ Bt,
               const float* __restrict__ bias, unsigned short* __restrict__ OutBf) {
  gemm_body<D_, H_, 4, true>(A, Bt, bias, OutBf, nullptr);
}

__global__ __launch_bounds__(512, 2)
void gemm_mlp2(const unsigned short* __restrict__ A, const unsigned short* __restrict__ Bt,
               const float* __restrict__ bias, float* __restrict__ OutF) {
  gemm_body<H_, D_, 1, false>(A, Bt, bias, nullptr, OutF);
}

extern "C" void kernel_launch(void* const* d_in, const int* in_sizes, int n_in,
                              void* d_out, int out_size, void* d_ws, size_t ws_size,
                              hipStream_t stream) {
  const float* x  = (const float*)d_in[0];
  const float* w1 = (const float*)d_in[1];
  const float* b1 = (const float*)d_in[2];
  const float* w2 = (const float*)d_in[3];
  const float* b2 = (const float*)d_in[4];
  float* out = (float*)d_out;

  const size_t xN  = (size_t)B_ * E_ * N_ * D_;
  const size_t w1N = (size_t)E_ * D_ * H_;
  const size_t w2N = (size_t)E_ * H_ * D_;
  const size_t hN  = (size_t)B_ * E_ * N_ * H_;
  const size_t needed = (xN + w1N + w2N + hN) * 2;
  if (ws_size < needed) return;

  unsigned short* xb  = (unsigned short*)d_ws;
  unsigned short* w1t = xb + xN;   // [E][H][D] bf16
  unsigned short* w2t = w1t + w1N; // [E][D][H] bf16
  unsigned short* hb  = w2t + w2N; // [B][E][N][H] bf16

  dim3 tb(32, 8);
  // Order: w2t first, then w1t, then xb -> GEMM1's inputs are L3-hottest.
  transpose_cvt_kernel<<<dim3(D_ / 32, H_ / 32, E_), tb, 0, stream>>>(w2, w2t, H_, D_);
  transpose_cvt_kernel<<<dim3(H_ / 32, D_ / 32, E_), tb, 0, stream>>>(w1, w1t, D_, H_);
  cvt_x_kernel<<<2048, 256, 0, stream>>>(x, xb, (int)(xN / 4));

  // GEMM1: h = gelu(x @ w1 + b1); 256 blocks, 4 n-tiles each
  gemm_mlp1<<<E_ * 8 * (H_ / 256 / 4), 512, 0, stream>>>(xb, w1t, b1, hb);
  // GEMM2: out = h @ w2 + b2; 256 blocks
  gemm_mlp2<<<E_ * 8 * (D_ / 256), 512, 0, stream>>>(hb, w2t, b2, out);
}